// Round 7
// baseline (86.198 us; speedup 1.0000x reference)
//
#include <hip/hip_runtime.h>
#include <cstdint>
#include <cstddef>

#define BS 8
#define NQ 16384
#define NG 1024
#define NC 5
#define BPB 4               // blocks per batch (scan duplicated, match split)
#define CAP 768             // LDS candidate capacity per class
#define SLACK 0.1514214f    // 0.1*sqrt(2) + 0.01 margin
#define FINF 3.0e38f

using u64 = unsigned long long;

// ---------- float top-4 (keep 4 smallest, sorted ascending) ----------
__device__ __forceinline__ void fce(float &x, float &y) {
    float lo = fminf(x, y), hi = fmaxf(x, y);
    x = lo; y = hi;
}
__device__ __forceinline__ void finsert(float k[4], float v) {
    float c = v, t;
    t = fminf(k[0], c); c = fmaxf(k[0], c); k[0] = t;
    t = fminf(k[1], c); c = fmaxf(k[1], c); k[1] = t;
    t = fminf(k[2], c); c = fmaxf(k[2], c); k[2] = t;
    k[3] = fminf(k[3], c);
}
__device__ __forceinline__ void fmerge4(float a[4], float b0, float b1, float b2, float b3) {
    float m0 = fminf(a[0], b3), m1 = fminf(a[1], b2), m2 = fminf(a[2], b1), m3 = fminf(a[3], b0);
    fce(m0, m2); fce(m1, m3); fce(m0, m1); fce(m2, m3);
    a[0] = m0; a[1] = m1; a[2] = m2; a[3] = m3;
}

// ---------- u64 keyed top-4 (exact, tie-break by low 32 = q) ----------
__device__ __forceinline__ void ce(u64 &x, u64 &y) {
    u64 lo = x < y ? x : y;
    u64 hi = x < y ? y : x;
    x = lo; y = hi;
}
__device__ __forceinline__ void merge4(u64 a[4], u64 b0, u64 b1, u64 b2, u64 b3) {
    u64 m0 = a[0] < b3 ? a[0] : b3;
    u64 m1 = a[1] < b2 ? a[1] : b2;
    u64 m2 = a[2] < b1 ? a[2] : b1;
    u64 m3 = a[3] < b0 ? a[3] : b0;
    ce(m0, m2); ce(m1, m3); ce(m0, m1); ce(m2, m3);
    a[0] = m0; a[1] = m1; a[2] = m2; a[3] = m3;
}
__device__ __forceinline__ void kinsert(u64 kk[4], float cost, unsigned q) {
    unsigned uu = __float_as_uint(cost);
    uu ^= ((unsigned)((int)uu >> 31)) | 0x80000000u;
    u64 k = ((u64)uu << 32) | q;
    if (k < kk[3]) { kk[3] = k; ce(kk[2], kk[3]); ce(kk[1], kk[2]); ce(kk[0], kk[1]); }
}

#define SOFTMAX5(lg, X0, X1, X2, X3, X4, S)                                     \
    float X0 = (lg)[0], X1 = (lg)[1], X2 = (lg)[2], X3 = (lg)[3], X4 = (lg)[4]; \
    {                                                                           \
        float mx_ = fmaxf(fmaxf(fmaxf(X0, X1), fmaxf(X2, X3)), X4);             \
        X0 = expf(X0 - mx_); X1 = expf(X1 - mx_); X2 = expf(X2 - mx_);          \
        X3 = expf(X3 - mx_); X4 = expf(X4 - mx_);                               \
    }                                                                           \
    float S = X0 + X1 + X2 + X3 + X4;

// One block = one (batch, quarter-of-gts). 1024 threads = 16 waves.
// Phase A: scan all NQ queries of the batch -> exact global top-4 prob per class.
// Phase B: threshold = P4* - SLACK; compact candidates into LDS lists.
// Phase C: 16 waves x 16 gts each, exact keyed top-4 over the class list.
// Correctness: a true top-4 query q* for a gt of class c must have
// p_c(q*) >= P4*(b,c) - 0.1*sqrt(2); else its cost exceeds the cost of all 4
// best-prob queries. SLACK adds 0.01 fp margin. Overflow (>CAP) -> brute scan.
__global__ __launch_bounds__(1024, 1) void fused_kernel(
        const float* __restrict__ pred_coords,   // [BS][NQ][2]
        const float* __restrict__ logits,        // [BS][NQ][NC]
        const float* __restrict__ gt_coords,     // [BS][NG][2]
        const int*   __restrict__ gt_labels,     // [BS][NG]
        const int*   __restrict__ gt_masks,      // [BS][NG]
        int*         __restrict__ out)           // [BS][4][NG]
{
    const int tid = threadIdx.x;
    const int wv = tid >> 6, lane = tid & 63;    // 16 waves
    const int b = blockIdx.x / BPB, part = blockIdx.x % BPB;

    __shared__ float    slds[16][NC][4];
    __shared__ float    Tsh[NC];
    __shared__ unsigned lcount[NC];
    __shared__ u64      lists[NC][CAP];

    const float* lgb = logits + (size_t)b * NQ * NC;

    // ---------------- phase A: exact per-class top-4 prob over the whole batch ----------------
    float nk[NC][4];
    #pragma unroll
    for (int c = 0; c < NC; ++c)
        #pragma unroll
        for (int j = 0; j < 4; ++j) nk[c][j] = FINF;

    #pragma unroll 4
    for (int r = 0; r < 16; ++r) {
        int q = r * 1024 + tid;
        const float* lg = lgb + (size_t)q * NC;
        SOFTMAX5(lg, x0, x1, x2, x3, x4, s);
        finsert(nk[0], -(x0 / s));
        finsert(nk[1], -(x1 / s));
        finsert(nk[2], -(x2 / s));
        finsert(nk[3], -(x3 / s));
        finsert(nk[4], -(x4 / s));
    }
    #pragma unroll
    for (int d = 1; d < 64; d <<= 1) {
        #pragma unroll
        for (int c = 0; c < NC; ++c) {
            float b0 = __shfl_xor(nk[c][0], d, 64);
            float b1 = __shfl_xor(nk[c][1], d, 64);
            float b2 = __shfl_xor(nk[c][2], d, 64);
            float b3 = __shfl_xor(nk[c][3], d, 64);
            fmerge4(nk[c], b0, b1, b2, b3);
        }
    }
    if (lane == 0) {
        #pragma unroll
        for (int c = 0; c < NC; ++c)
            #pragma unroll
            for (int j = 0; j < 4; ++j) slds[wv][c][j] = nk[c][j];
    }
    if (tid < NC) lcount[tid] = 0u;
    __syncthreads();
    if (tid < NC) {
        float a[4] = {slds[0][tid][0], slds[0][tid][1], slds[0][tid][2], slds[0][tid][3]};
        #pragma unroll
        for (int w = 1; w < 16; ++w)
            fmerge4(a, slds[w][tid][0], slds[w][tid][1], slds[w][tid][2], slds[w][tid][3]);
        Tsh[tid] = -a[3] - SLACK;            // P4*(b,c) - slack
    }
    __syncthreads();

    // ---------------- phase B: compact candidates (ballot-rank + LDS atomic base) ----------------
    float T0 = Tsh[0], T1 = Tsh[1], T2 = Tsh[2], T3 = Tsh[3], T4 = Tsh[4];
    #pragma unroll 2
    for (int r = 0; r < 16; ++r) {
        int q = r * 1024 + tid;
        const float* lg = lgb + (size_t)q * NC;
        SOFTMAX5(lg, x0, x1, x2, x3, x4, s);
        float pv[NC] = {x0 / s, x1 / s, x2 / s, x3 / s, x4 / s};
        float Tv[NC] = {T0, T1, T2, T3, T4};
        #pragma unroll
        for (int c = 0; c < NC; ++c) {
            bool pass = (pv[c] >= Tv[c]);
            u64 m = __ballot(pass);
            if (m) {
                unsigned base = 0;
                if (lane == 0) base = atomicAdd(&lcount[c], (unsigned)__popcll(m));
                base = __shfl((int)base, 0, 64);
                if (pass) {
                    unsigned slot = base + (unsigned)__popcll(m & ((1ull << lane) - 1ull));
                    if (slot < CAP)
                        lists[c][slot] = ((u64)__float_as_uint(pv[c]) << 32) | (unsigned)q;
                }
            }
        }
    }
    __syncthreads();

    // ---------------- phase C: exact keyed top-4 per gt (16 gts per wave) ----------------
    const float2* pc = reinterpret_cast<const float2*>(pred_coords) + (size_t)b * NQ;
    #pragma unroll 1
    for (int i = 0; i < 16; ++i) {
        int g = part * (NG / BPB) + i * 16 + wv;
        int m = gt_masks[b * NG + g];
        u64 kk[4] = {~0ull, ~0ull, ~0ull, ~0ull};
        if (m) {
            int c = gt_labels[b * NG + g];
            float2 gc = reinterpret_cast<const float2*>(gt_coords)[(size_t)b * NG + g];
            float gx = gc.x, gy = gc.y, gb2 = gc.x * gc.x + gc.y * gc.y;
            unsigned n = lcount[c];
            if (n <= CAP) {
                for (unsigned j = lane; j < n; j += 64) {
                    u64 e = lists[c][j];
                    float p = __uint_as_float((unsigned)(e >> 32));
                    unsigned qq = (unsigned)(e & 0xFFFFFFFFu);
                    float2 cq = pc[qq];
                    float d2 = fmaxf(cq.x * cq.x + cq.y * cq.y + gb2
                                     - 2.0f * (cq.x * gx + cq.y * gy), 0.0f);
                    kinsert(kk, 0.1f * sqrtf(d2) - p, qq);
                }
            } else {
                // overflow fallback: exact brute scan (same numerics)
                for (int q2 = lane; q2 < NQ; q2 += 64) {
                    const float* lg2 = lgb + (size_t)q2 * NC;
                    SOFTMAX5(lg2, y0, y1, y2, y3, y4, s2);
                    float num = (c == 0) ? y0 : (c == 1) ? y1 : (c == 2) ? y2 : (c == 3) ? y3 : y4;
                    float p = num / s2;
                    float2 cq = pc[q2];
                    float d2 = fmaxf(cq.x * cq.x + cq.y * cq.y + gb2
                                     - 2.0f * (cq.x * gx + cq.y * gy), 0.0f);
                    kinsert(kk, 0.1f * sqrtf(d2) - p, (unsigned)q2);
                }
            }
            #pragma unroll
            for (int d = 1; d < 64; d <<= 1) {
                u64 b0 = __shfl_xor(kk[0], d, 64);
                u64 b1 = __shfl_xor(kk[1], d, 64);
                u64 b2_ = __shfl_xor(kk[2], d, 64);
                u64 b3 = __shfl_xor(kk[3], d, 64);
                merge4(kk, b0, b1, b2_, b3);
            }
        }
        if (lane < 4) {
            u64 sel = (lane == 0) ? kk[0] : (lane == 1) ? kk[1] : (lane == 2) ? kk[2] : kk[3];
            int idx = m ? (int)(sel & 0xFFFFFFFFull) : lane;
            out[((size_t)(b * 4 + lane) << 10) + g] = idx;
        }
    }
}

extern "C" void kernel_launch(void* const* d_in, const int* in_sizes, int n_in,
                              void* d_out, int out_size, void* d_ws, size_t ws_size,
                              hipStream_t stream) {
    const float* pred_coords = (const float*)d_in[0];
    const float* pred_logits = (const float*)d_in[1];
    const float* gt_coords   = (const float*)d_in[2];
    const int*   gt_labels   = (const int*)d_in[3];
    const int*   gt_masks    = (const int*)d_in[4];
    int* out = (int*)d_out;

    fused_kernel<<<BS * BPB, 1024, 0, stream>>>(
        pred_coords, pred_logits, gt_coords, gt_labels, gt_masks, out);
}

// Round 8
// 57.088 us; speedup vs baseline: 1.5099x; 1.5099x over previous
//
#include <hip/hip_runtime.h>
#include <cstdint>
#include <cstddef>

#define BS 8
#define NQ 16384
#define NG 1024
#define NC 5
#define BPB 32              // blocks per batch -> grid 256 = 1 block/CU
#define CAP 1536            // LDS candidate capacity per class (5*1536*8 = 60 KB)
#define SLACK 0.1514214f    // 0.1*sqrt(2) + 0.01 margin
#define FINF 3.0e38f

using u64 = unsigned long long;

// ---------- float top-4 (keep 4 smallest, sorted ascending) ----------
__device__ __forceinline__ void fce(float &x, float &y) {
    float lo = fminf(x, y), hi = fmaxf(x, y);
    x = lo; y = hi;
}
__device__ __forceinline__ void finsert(float k[4], float v) {
    float c = v, t;
    t = fminf(k[0], c); c = fmaxf(k[0], c); k[0] = t;
    t = fminf(k[1], c); c = fmaxf(k[1], c); k[1] = t;
    t = fminf(k[2], c); c = fmaxf(k[2], c); k[2] = t;
    k[3] = fminf(k[3], c);
}
__device__ __forceinline__ void fmerge4(float a[4], float b0, float b1, float b2, float b3) {
    float m0 = fminf(a[0], b3), m1 = fminf(a[1], b2), m2 = fminf(a[2], b1), m3 = fminf(a[3], b0);
    fce(m0, m2); fce(m1, m3); fce(m0, m1); fce(m2, m3);
    a[0] = m0; a[1] = m1; a[2] = m2; a[3] = m3;
}

// ---------- u64 keyed top-4 (exact, tie-break by low 32 = q) ----------
__device__ __forceinline__ void ce(u64 &x, u64 &y) {
    u64 lo = x < y ? x : y;
    u64 hi = x < y ? y : x;
    x = lo; y = hi;
}
__device__ __forceinline__ void merge4(u64 a[4], u64 b0, u64 b1, u64 b2, u64 b3) {
    u64 m0 = a[0] < b3 ? a[0] : b3;
    u64 m1 = a[1] < b2 ? a[1] : b2;
    u64 m2 = a[2] < b1 ? a[2] : b1;
    u64 m3 = a[3] < b0 ? a[3] : b0;
    ce(m0, m2); ce(m1, m3); ce(m0, m1); ce(m2, m3);
    a[0] = m0; a[1] = m1; a[2] = m2; a[3] = m3;
}
__device__ __forceinline__ void kinsert(u64 kk[4], float cost, unsigned q) {
    unsigned uu = __float_as_uint(cost);
    uu ^= ((unsigned)((int)uu >> 31)) | 0x80000000u;
    u64 k = ((u64)uu << 32) | q;
    if (k < kk[3]) { kk[3] = k; ce(kk[2], kk[3]); ce(kk[1], kk[2]); ce(kk[0], kk[1]); }
}

#define SOFTMAX5(lg, X0, X1, X2, X3, X4, S)                                     \
    float X0 = (lg)[0], X1 = (lg)[1], X2 = (lg)[2], X3 = (lg)[3], X4 = (lg)[4]; \
    {                                                                           \
        float mx_ = fmaxf(fmaxf(fmaxf(X0, X1), fmaxf(X2, X3)), X4);             \
        X0 = expf(X0 - mx_); X1 = expf(X1 - mx_); X2 = expf(X2 - mx_);          \
        X3 = expf(X3 - mx_); X4 = expf(X4 - mx_);                               \
    }                                                                           \
    float S = X0 + X1 + X2 + X3 + X4;

// One block = one (batch, 1/32 of gts). 1024 threads = 16 waves, 1 block/CU.
// Phase A: scan all NQ of the batch -> exact global top-4 prob per class.
// Phase B: threshold = P4* - SLACK; compact candidates into LDS lists.
// Phase C: 16 waves x 2 gts each, exact keyed top-4 over the class list.
// Correctness: a true top-4 query q* for a gt of class c has
// p_c(q*) >= P4*(b,c) - 0.1*sqrt(2) (else all 4 best-prob queries beat it).
// SLACK adds 0.01 fp margin. Overflow (>CAP) -> exact brute scan.
__global__ __launch_bounds__(1024, 1) void fused_kernel(
        const float* __restrict__ pred_coords,   // [BS][NQ][2]
        const float* __restrict__ logits,        // [BS][NQ][NC]
        const float* __restrict__ gt_coords,     // [BS][NG][2]
        const int*   __restrict__ gt_labels,     // [BS][NG]
        const int*   __restrict__ gt_masks,      // [BS][NG]
        int*         __restrict__ out)           // [BS][4][NG]
{
    const int tid = threadIdx.x;
    const int wv = tid >> 6, lane = tid & 63;    // 16 waves
    const int b = blockIdx.x / BPB, part = blockIdx.x % BPB;

    __shared__ float    slds[16][NC][4];
    __shared__ float    Tsh[NC];
    __shared__ unsigned lcount[NC];
    __shared__ u64      lists[NC][CAP];          // 60 KB

    const float* lgb = logits + (size_t)b * NQ * NC;

    // ---------------- phase A: exact per-class top-4 prob over the whole batch ----------------
    float nk[NC][4];
    #pragma unroll
    for (int c = 0; c < NC; ++c)
        #pragma unroll
        for (int j = 0; j < 4; ++j) nk[c][j] = FINF;

    #pragma unroll 4
    for (int r = 0; r < 16; ++r) {
        int q = r * 1024 + tid;
        const float* lg = lgb + (size_t)q * NC;
        SOFTMAX5(lg, x0, x1, x2, x3, x4, s);
        finsert(nk[0], -(x0 / s));
        finsert(nk[1], -(x1 / s));
        finsert(nk[2], -(x2 / s));
        finsert(nk[3], -(x3 / s));
        finsert(nk[4], -(x4 / s));
    }
    #pragma unroll
    for (int d = 1; d < 64; d <<= 1) {
        #pragma unroll
        for (int c = 0; c < NC; ++c) {
            float b0 = __shfl_xor(nk[c][0], d, 64);
            float b1 = __shfl_xor(nk[c][1], d, 64);
            float b2 = __shfl_xor(nk[c][2], d, 64);
            float b3 = __shfl_xor(nk[c][3], d, 64);
            fmerge4(nk[c], b0, b1, b2, b3);
        }
    }
    if (lane == 0) {
        #pragma unroll
        for (int c = 0; c < NC; ++c)
            #pragma unroll
            for (int j = 0; j < 4; ++j) slds[wv][c][j] = nk[c][j];
    }
    if (tid < NC) lcount[tid] = 0u;
    __syncthreads();
    if (tid < NC) {
        float a[4] = {slds[0][tid][0], slds[0][tid][1], slds[0][tid][2], slds[0][tid][3]};
        #pragma unroll
        for (int w = 1; w < 16; ++w)
            fmerge4(a, slds[w][tid][0], slds[w][tid][1], slds[w][tid][2], slds[w][tid][3]);
        Tsh[tid] = -a[3] - SLACK;            // P4*(b,c) - slack
    }
    __syncthreads();

    // ---------------- phase B: compact candidates (ballot-rank + LDS atomic base) ----------------
    float T0 = Tsh[0], T1 = Tsh[1], T2 = Tsh[2], T3 = Tsh[3], T4 = Tsh[4];
    #pragma unroll 2
    for (int r = 0; r < 16; ++r) {
        int q = r * 1024 + tid;
        const float* lg = lgb + (size_t)q * NC;
        SOFTMAX5(lg, x0, x1, x2, x3, x4, s);
        float pv[NC] = {x0 / s, x1 / s, x2 / s, x3 / s, x4 / s};
        float Tv[NC] = {T0, T1, T2, T3, T4};
        #pragma unroll
        for (int c = 0; c < NC; ++c) {
            bool pass = (pv[c] >= Tv[c]);
            u64 m = __ballot(pass);
            if (m) {
                unsigned base = 0;
                if (lane == 0) base = atomicAdd(&lcount[c], (unsigned)__popcll(m));
                base = __shfl((int)base, 0, 64);
                if (pass) {
                    unsigned slot = base + (unsigned)__popcll(m & ((1ull << lane) - 1ull));
                    if (slot < CAP)
                        lists[c][slot] = ((u64)__float_as_uint(pv[c]) << 32) | (unsigned)q;
                }
            }
        }
    }
    __syncthreads();

    // ---------------- phase C: exact keyed top-4 per gt (2 gts per wave) ----------------
    const float2* pc = reinterpret_cast<const float2*>(pred_coords) + (size_t)b * NQ;
    #pragma unroll 1
    for (int i = 0; i < 2; ++i) {
        int g = part * (NG / BPB) + i * 16 + wv;
        int m = gt_masks[b * NG + g];
        u64 kk[4] = {~0ull, ~0ull, ~0ull, ~0ull};
        if (m) {
            int c = gt_labels[b * NG + g];
            float2 gc = reinterpret_cast<const float2*>(gt_coords)[(size_t)b * NG + g];
            float gx = gc.x, gy = gc.y, gb2 = gc.x * gc.x + gc.y * gc.y;
            unsigned n = lcount[c];
            if (n <= CAP) {
                for (unsigned j = lane; j < n; j += 64) {
                    u64 e = lists[c][j];
                    float p = __uint_as_float((unsigned)(e >> 32));
                    unsigned qq = (unsigned)(e & 0xFFFFFFFFu);
                    float2 cq = pc[qq];
                    float d2 = fmaxf(cq.x * cq.x + cq.y * cq.y + gb2
                                     - 2.0f * (cq.x * gx + cq.y * gy), 0.0f);
                    kinsert(kk, 0.1f * sqrtf(d2) - p, qq);
                }
            } else {
                // overflow fallback: exact brute scan (same numerics)
                for (int q2 = lane; q2 < NQ; q2 += 64) {
                    const float* lg2 = lgb + (size_t)q2 * NC;
                    SOFTMAX5(lg2, y0, y1, y2, y3, y4, s2);
                    float num = (c == 0) ? y0 : (c == 1) ? y1 : (c == 2) ? y2 : (c == 3) ? y3 : y4;
                    float p = num / s2;
                    float2 cq = pc[q2];
                    float d2 = fmaxf(cq.x * cq.x + cq.y * cq.y + gb2
                                     - 2.0f * (cq.x * gx + cq.y * gy), 0.0f);
                    kinsert(kk, 0.1f * sqrtf(d2) - p, (unsigned)q2);
                }
            }
            #pragma unroll
            for (int d = 1; d < 64; d <<= 1) {
                u64 b0 = __shfl_xor(kk[0], d, 64);
                u64 b1 = __shfl_xor(kk[1], d, 64);
                u64 b2_ = __shfl_xor(kk[2], d, 64);
                u64 b3 = __shfl_xor(kk[3], d, 64);
                merge4(kk, b0, b1, b2_, b3);
            }
        }
        if (lane < 4) {
            u64 sel = (lane == 0) ? kk[0] : (lane == 1) ? kk[1] : (lane == 2) ? kk[2] : kk[3];
            int idx = m ? (int)(sel & 0xFFFFFFFFull) : lane;
            out[((size_t)(b * 4 + lane) << 10) + g] = idx;
        }
    }
}

extern "C" void kernel_launch(void* const* d_in, const int* in_sizes, int n_in,
                              void* d_out, int out_size, void* d_ws, size_t ws_size,
                              hipStream_t stream) {
    const float* pred_coords = (const float*)d_in[0];
    const float* pred_logits = (const float*)d_in[1];
    const float* gt_coords   = (const float*)d_in[2];
    const int*   gt_labels   = (const int*)d_in[3];
    const int*   gt_masks    = (const int*)d_in[4];
    int* out = (int*)d_out;

    fused_kernel<<<BS * BPB, 1024, 0, stream>>>(
        pred_coords, pred_logits, gt_coords, gt_labels, gt_masks, out);
}

// Round 9
// 50.982 us; speedup vs baseline: 1.6908x; 1.1198x over previous
//
#include <hip/hip_runtime.h>
#include <cstdint>
#include <cstddef>

#define BS 8
#define NQ 16384
#define NG 1024
#define NC 5
#define BPB 32              // blocks per batch -> grid 256 = 1 block/CU
#define CAP 1536            // LDS candidate capacity per class (5*1536*8 = 60 KB)
#define SLACK 0.1514214f    // 0.1*sqrt(2) + 0.01 margin (>> 2*eps_fastmath ~ 6e-6)
#define FINF 3.0e38f

using u64 = unsigned long long;

// ---------- float top-4 (keep 4 smallest, sorted ascending) ----------
__device__ __forceinline__ void fce(float &x, float &y) {
    float lo = fminf(x, y), hi = fmaxf(x, y);
    x = lo; y = hi;
}
__device__ __forceinline__ void finsert(float k[4], float v) {
    float c = v, t;
    t = fminf(k[0], c); c = fmaxf(k[0], c); k[0] = t;
    t = fminf(k[1], c); c = fmaxf(k[1], c); k[1] = t;
    t = fminf(k[2], c); c = fmaxf(k[2], c); k[2] = t;
    k[3] = fminf(k[3], c);
}
__device__ __forceinline__ void fmerge4(float a[4], float b0, float b1, float b2, float b3) {
    float m0 = fminf(a[0], b3), m1 = fminf(a[1], b2), m2 = fminf(a[2], b1), m3 = fminf(a[3], b0);
    fce(m0, m2); fce(m1, m3); fce(m0, m1); fce(m2, m3);
    a[0] = m0; a[1] = m1; a[2] = m2; a[3] = m3;
}

// ---------- u64 keyed top-4 (exact, tie-break by low 32 = q) ----------
__device__ __forceinline__ void ce(u64 &x, u64 &y) {
    u64 lo = x < y ? x : y;
    u64 hi = x < y ? y : x;
    x = lo; y = hi;
}
__device__ __forceinline__ void merge4(u64 a[4], u64 b0, u64 b1, u64 b2, u64 b3) {
    u64 m0 = a[0] < b3 ? a[0] : b3;
    u64 m1 = a[1] < b2 ? a[1] : b2;
    u64 m2 = a[2] < b1 ? a[2] : b1;
    u64 m3 = a[3] < b0 ? a[3] : b0;
    ce(m0, m2); ce(m1, m3); ce(m0, m1); ce(m2, m3);
    a[0] = m0; a[1] = m1; a[2] = m2; a[3] = m3;
}
__device__ __forceinline__ void kinsert(u64 kk[4], float cost, unsigned q) {
    unsigned uu = __float_as_uint(cost);
    uu ^= ((unsigned)((int)uu >> 31)) | 0x80000000u;
    u64 k = ((u64)uu << 32) | q;
    if (k < kk[3]) { kk[3] = k; ce(kk[2], kk[3]); ce(kk[1], kk[2]); ce(kk[0], kk[1]); }
}

// exact softmax numerics — identical to all prior passing rounds
#define SOFTMAX5(lg, X0, X1, X2, X3, X4, S)                                     \
    float X0 = (lg)[0], X1 = (lg)[1], X2 = (lg)[2], X3 = (lg)[3], X4 = (lg)[4]; \
    {                                                                           \
        float mx_ = fmaxf(fmaxf(fmaxf(X0, X1), fmaxf(X2, X3)), X4);             \
        X0 = expf(X0 - mx_); X1 = expf(X1 - mx_); X2 = expf(X2 - mx_);          \
        X3 = expf(X3 - mx_); X4 = expf(X4 - mx_);                               \
    }                                                                           \
    float S = X0 + X1 + X2 + X3 + X4;

// fast approximate softmax (v_exp + v_rcp), only for threshold scan/test.
// |p_fast - p_exact| <= ~3e-6, absorbed by SLACK margin.
#define SOFTMAX5_FAST(lg, Q0, Q1, Q2, Q3, Q4)                                   \
    float Q0, Q1, Q2, Q3, Q4;                                                   \
    {                                                                           \
        float y0 = (lg)[0], y1 = (lg)[1], y2 = (lg)[2], y3 = (lg)[3], y4 = (lg)[4]; \
        float mx_ = fmaxf(fmaxf(fmaxf(y0, y1), fmaxf(y2, y3)), y4);             \
        float e0 = __expf(y0 - mx_), e1 = __expf(y1 - mx_), e2 = __expf(y2 - mx_); \
        float e3 = __expf(y3 - mx_), e4 = __expf(y4 - mx_);                     \
        float rs_ = __builtin_amdgcn_rcpf(e0 + e1 + e2 + e3 + e4);              \
        Q0 = e0 * rs_; Q1 = e1 * rs_; Q2 = e2 * rs_; Q3 = e3 * rs_; Q4 = e4 * rs_; \
    }

// One block = one (batch, 1/32 of gts). 1024 threads = 16 waves, 1 block/CU.
// Phase A (fast math): scan batch -> approx global top-4 prob per class.
// Phase B (fast test, exact store): threshold = P4*_approx - SLACK; passing
//   lanes recompute the EXACT p (expf + x/s, bit-identical to prior rounds)
//   and compact (p_exact, q) into LDS lists.
// Phase C: 16 waves x 2 gts, exact keyed top-4 over the class list.
// Prune correctness: true top-4 q* has p_exact >= P4*_exact - 0.1*sqrt(2);
// fast-math error eps<=~3e-6 per side needs SLACK >= 0.1*sqrt(2)+2eps. ✓
// Overflow (>CAP) -> exact brute scan fallback.
__global__ __launch_bounds__(1024, 1) void fused_kernel(
        const float* __restrict__ pred_coords,   // [BS][NQ][2]
        const float* __restrict__ logits,        // [BS][NQ][NC]
        const float* __restrict__ gt_coords,     // [BS][NG][2]
        const int*   __restrict__ gt_labels,     // [BS][NG]
        const int*   __restrict__ gt_masks,      // [BS][NG]
        int*         __restrict__ out)           // [BS][4][NG]
{
    const int tid = threadIdx.x;
    const int wv = tid >> 6, lane = tid & 63;    // 16 waves
    const int b = blockIdx.x / BPB, part = blockIdx.x % BPB;

    __shared__ float    slds[16][NC][4];
    __shared__ float    Tsh[NC];
    __shared__ unsigned lcount[NC];
    __shared__ u64      lists[NC][CAP];          // 60 KB

    const float* lgb = logits + (size_t)b * NQ * NC;

    // ---------------- phase A: approx per-class top-4 prob over the whole batch ----------------
    float nk[NC][4];
    #pragma unroll
    for (int c = 0; c < NC; ++c)
        #pragma unroll
        for (int j = 0; j < 4; ++j) nk[c][j] = FINF;

    #pragma unroll 4
    for (int r = 0; r < 16; ++r) {
        int q = r * 1024 + tid;
        const float* lg = lgb + (size_t)q * NC;
        SOFTMAX5_FAST(lg, q0, q1, q2, q3, q4);
        finsert(nk[0], -q0);
        finsert(nk[1], -q1);
        finsert(nk[2], -q2);
        finsert(nk[3], -q3);
        finsert(nk[4], -q4);
    }
    #pragma unroll
    for (int d = 1; d < 64; d <<= 1) {
        #pragma unroll
        for (int c = 0; c < NC; ++c) {
            float b0 = __shfl_xor(nk[c][0], d, 64);
            float b1 = __shfl_xor(nk[c][1], d, 64);
            float b2 = __shfl_xor(nk[c][2], d, 64);
            float b3 = __shfl_xor(nk[c][3], d, 64);
            fmerge4(nk[c], b0, b1, b2, b3);
        }
    }
    if (lane == 0) {
        #pragma unroll
        for (int c = 0; c < NC; ++c)
            #pragma unroll
            for (int j = 0; j < 4; ++j) slds[wv][c][j] = nk[c][j];
    }
    if (tid < NC) lcount[tid] = 0u;
    __syncthreads();
    if (tid < NC) {
        float a[4] = {slds[0][tid][0], slds[0][tid][1], slds[0][tid][2], slds[0][tid][3]};
        #pragma unroll
        for (int w = 1; w < 16; ++w)
            fmerge4(a, slds[w][tid][0], slds[w][tid][1], slds[w][tid][2], slds[w][tid][3]);
        Tsh[tid] = -a[3] - SLACK;            // P4*_approx(b,c) - slack
    }
    __syncthreads();

    // ---------------- phase B: fast test; exact recompute+store for passers ----------------
    float T0 = Tsh[0], T1 = Tsh[1], T2 = Tsh[2], T3 = Tsh[3], T4 = Tsh[4];
    #pragma unroll 2
    for (int r = 0; r < 16; ++r) {
        int q = r * 1024 + tid;
        const float* lg = lgb + (size_t)q * NC;
        SOFTMAX5_FAST(lg, q0, q1, q2, q3, q4);
        unsigned pm = (q0 >= T0 ? 1u : 0u) | (q1 >= T1 ? 2u : 0u) | (q2 >= T2 ? 4u : 0u)
                    | (q3 >= T3 ? 8u : 0u) | (q4 >= T4 ? 16u : 0u);
        float pe0 = 0.f, pe1 = 0.f, pe2 = 0.f, pe3 = 0.f, pe4 = 0.f;
        if (pm) {                            // rare (~7% of lanes): exact numerics for storage
            SOFTMAX5(lg, x0, x1, x2, x3, x4, s);
            pe0 = x0 / s; pe1 = x1 / s; pe2 = x2 / s; pe3 = x3 / s; pe4 = x4 / s;
        }
        #pragma unroll
        for (int c = 0; c < NC; ++c) {
            bool pass = (pm >> c) & 1u;
            u64 m = __ballot(pass);
            if (m) {
                unsigned base = 0;
                if (lane == 0) base = atomicAdd(&lcount[c], (unsigned)__popcll(m));
                base = __shfl((int)base, 0, 64);
                if (pass) {
                    unsigned slot = base + (unsigned)__popcll(m & ((1ull << lane) - 1ull));
                    float pe = (c == 0) ? pe0 : (c == 1) ? pe1 : (c == 2) ? pe2 : (c == 3) ? pe3 : pe4;
                    if (slot < CAP)
                        lists[c][slot] = ((u64)__float_as_uint(pe) << 32) | (unsigned)q;
                }
            }
        }
    }
    __syncthreads();

    // ---------------- phase C: exact keyed top-4 per gt (2 gts per wave) ----------------
    const float2* pc = reinterpret_cast<const float2*>(pred_coords) + (size_t)b * NQ;
    #pragma unroll 1
    for (int i = 0; i < 2; ++i) {
        int g = part * (NG / BPB) + i * 16 + wv;
        int m = gt_masks[b * NG + g];
        u64 kk[4] = {~0ull, ~0ull, ~0ull, ~0ull};
        if (m) {
            int c = gt_labels[b * NG + g];
            float2 gc = reinterpret_cast<const float2*>(gt_coords)[(size_t)b * NG + g];
            float gx = gc.x, gy = gc.y, gb2 = gc.x * gc.x + gc.y * gc.y;
            unsigned n = lcount[c];
            if (n <= CAP) {
                for (unsigned j = lane; j < n; j += 64) {
                    u64 e = lists[c][j];
                    float p = __uint_as_float((unsigned)(e >> 32));
                    unsigned qq = (unsigned)(e & 0xFFFFFFFFu);
                    float2 cq = pc[qq];
                    float d2 = fmaxf(cq.x * cq.x + cq.y * cq.y + gb2
                                     - 2.0f * (cq.x * gx + cq.y * gy), 0.0f);
                    kinsert(kk, 0.1f * sqrtf(d2) - p, qq);
                }
            } else {
                // overflow fallback: exact brute scan (same numerics)
                for (int q2 = lane; q2 < NQ; q2 += 64) {
                    const float* lg2 = lgb + (size_t)q2 * NC;
                    SOFTMAX5(lg2, y0, y1, y2, y3, y4, s2);
                    float num = (c == 0) ? y0 : (c == 1) ? y1 : (c == 2) ? y2 : (c == 3) ? y3 : y4;
                    float p = num / s2;
                    float2 cq = pc[q2];
                    float d2 = fmaxf(cq.x * cq.x + cq.y * cq.y + gb2
                                     - 2.0f * (cq.x * gx + cq.y * gy), 0.0f);
                    kinsert(kk, 0.1f * sqrtf(d2) - p, (unsigned)q2);
                }
            }
            #pragma unroll
            for (int d = 1; d < 64; d <<= 1) {
                u64 b0 = __shfl_xor(kk[0], d, 64);
                u64 b1 = __shfl_xor(kk[1], d, 64);
                u64 b2_ = __shfl_xor(kk[2], d, 64);
                u64 b3 = __shfl_xor(kk[3], d, 64);
                merge4(kk, b0, b1, b2_, b3);
            }
        }
        if (lane < 4) {
            u64 sel = (lane == 0) ? kk[0] : (lane == 1) ? kk[1] : (lane == 2) ? kk[2] : kk[3];
            int idx = m ? (int)(sel & 0xFFFFFFFFull) : lane;
            out[((size_t)(b * 4 + lane) << 10) + g] = idx;
        }
    }
}

extern "C" void kernel_launch(void* const* d_in, const int* in_sizes, int n_in,
                              void* d_out, int out_size, void* d_ws, size_t ws_size,
                              hipStream_t stream) {
    const float* pred_coords = (const float*)d_in[0];
    const float* pred_logits = (const float*)d_in[1];
    const float* gt_coords   = (const float*)d_in[2];
    const int*   gt_labels   = (const int*)d_in[3];
    const int*   gt_masks    = (const int*)d_in[4];
    int* out = (int*)d_out;

    fused_kernel<<<BS * BPB, 1024, 0, stream>>>(
        pred_coords, pred_logits, gt_coords, gt_labels, gt_masks, out);
}

// Round 10
// 28.559 us; speedup vs baseline: 3.0182x; 1.7851x over previous
//
#include <hip/hip_runtime.h>
#include <cstdint>
#include <cstddef>

#define BS 8
#define NQ 16384
#define NG 1024
#define NC 5
#define BPB 32              // blocks per batch -> grid 256 = 1 block/CU
#define LCAP 12032          // stage-1 packed candidate list (48 KB LDS)
#define CAP 400             // per-class exact candidate list (16 KB LDS)
#define PREF 0.55f          // static argmax-prob prefilter
#define SLACK 0.1514214f    // 0.1*sqrt(2) + 0.01 margin
#define B2EPS 1e-3f         // quantization/fast-math slop on the list filter

using u64 = unsigned long long;
typedef unsigned int u32;

// ---------- u64 keyed top-4 (exact, tie-break by low 32 = q) ----------
__device__ __forceinline__ void ce(u64 &x, u64 &y) {
    u64 lo = x < y ? x : y;
    u64 hi = x < y ? y : x;
    x = lo; y = hi;
}
__device__ __forceinline__ void merge4(u64 a[4], u64 b0, u64 b1, u64 b2, u64 b3) {
    u64 m0 = a[0] < b3 ? a[0] : b3;
    u64 m1 = a[1] < b2 ? a[1] : b2;
    u64 m2 = a[2] < b1 ? a[2] : b1;
    u64 m3 = a[3] < b0 ? a[3] : b0;
    ce(m0, m2); ce(m1, m3); ce(m0, m1); ce(m2, m3);
    a[0] = m0; a[1] = m1; a[2] = m2; a[3] = m3;
}
__device__ __forceinline__ void kinsert(u64 kk[4], float cost, unsigned q) {
    unsigned uu = __float_as_uint(cost);
    uu ^= ((unsigned)((int)uu >> 31)) | 0x80000000u;
    u64 k = ((u64)uu << 32) | q;
    if (k < kk[3]) { kk[3] = k; ce(kk[2], kk[3]); ce(kk[1], kk[2]); ce(kk[0], kk[1]); }
}

// ---------- u32 descending top-4 (for packed keys) ----------
__device__ __forceinline__ u32 umaxu(u32 a, u32 b) { return a > b ? a : b; }
__device__ __forceinline__ u32 uminu(u32 a, u32 b) { return a < b ? a : b; }
__device__ __forceinline__ void uce_desc(u32 &x, u32 &y) {
    u32 hi = umaxu(x, y), lo = uminu(x, y); x = hi; y = lo;
}
__device__ __forceinline__ void uinsert_desc(u32 k[4], u32 v) {
    u32 t;
    t = umaxu(k[0], v); v = uminu(k[0], v); k[0] = t;
    t = umaxu(k[1], v); v = uminu(k[1], v); k[1] = t;
    t = umaxu(k[2], v); v = uminu(k[2], v); k[2] = t;
    k[3] = umaxu(k[3], v);
}
__device__ __forceinline__ void umerge4_desc(u32 a[4], u32 b0, u32 b1, u32 b2, u32 b3) {
    u32 m0 = umaxu(a[0], b3), m1 = umaxu(a[1], b2), m2 = umaxu(a[2], b1), m3 = umaxu(a[3], b0);
    uce_desc(m0, m2); uce_desc(m1, m3); uce_desc(m0, m1); uce_desc(m2, m3);
    a[0] = m0; a[1] = m1; a[2] = m2; a[3] = m3;
}

// exact softmax numerics — identical to all prior passing rounds
#define SOFTMAX5(lg, X0, X1, X2, X3, X4, S)                                     \
    float X0 = (lg)[0], X1 = (lg)[1], X2 = (lg)[2], X3 = (lg)[3], X4 = (lg)[4]; \
    {                                                                           \
        float mx_ = fmaxf(fmaxf(fmaxf(X0, X1), fmaxf(X2, X3)), X4);             \
        X0 = expf(X0 - mx_); X1 = expf(X1 - mx_); X2 = expf(X2 - mx_);          \
        X3 = expf(X3 - mx_); X4 = expf(X4 - mx_);                               \
    }                                                                           \
    float S = X0 + X1 + X2 + X3 + X4;

// Single-pass argmax prune:
//  P1: one scan; per q: p* = rcp(sum) (argmax prob, fast), pack (p15,c*,q) u32
//      into LDS list L if p* >= PREF.
//  A2: per-class top-4 of L -> T_c = P4_est - SLACK. Flags (-> exact brute
//      for that class's gts) when: L overflow, class count<4, T_c < PREF,
//      or per-class CAP overflow. Correctness: candidate (q,c) needs
//      p_c >= T_c > 0.5 => c is q's argmax AND p* >= PREF => q in L.
//      P4_est from argmax-subset, quantized down => <= true P4*. All
//      approx errors (rcp/quant ~2e-5) sit inside SLACK's 0.01 spare.
//  B2: filter L (+B2EPS slop); accepted entries get EXACT p (expf + x/s,
//      bit-identical to prior rounds) into lists[c].
//  C : exact keyed top-4 per gt over lists[c] (or brute if flagged).
__global__ __launch_bounds__(1024, 1) void fused_kernel(
        const float* __restrict__ pred_coords,   // [BS][NQ][2]
        const float* __restrict__ logits,        // [BS][NQ][NC]
        const float* __restrict__ gt_coords,     // [BS][NG][2]
        const int*   __restrict__ gt_labels,     // [BS][NG]
        const int*   __restrict__ gt_masks,      // [BS][NG]
        int*         __restrict__ out)           // [BS][4][NG]
{
    const int tid = threadIdx.x;
    const int wv = tid >> 6, lane = tid & 63;    // 16 waves
    const int b = blockIdx.x / BPB, part = blockIdx.x % BPB;

    __shared__ u64  lists[NC][CAP];              // 16000 B (8B-aligned first)
    __shared__ u32  L[LCAP];                     // 48128 B
    __shared__ u32  a2buf[15][4];
    __shared__ u32  a2cnt[15];
    __shared__ float Tsh[NC];
    __shared__ u32  lcount[NC];
    __shared__ u32  lcnt;
    __shared__ u32  flags;

    if (tid == 0) { lcnt = 0u; flags = 0u; }
    if (tid < NC) lcount[tid] = 0u;
    __syncthreads();

    const float* lgb = logits + (size_t)b * NQ * NC;

    // ---------------- pass 1: single scan, argmax prob only ----------------
    #pragma unroll 2
    for (int r = 0; r < 16; ++r) {
        int q = r * 1024 + tid;
        const float* lg = lgb + (size_t)q * NC;
        float l0 = lg[0], l1 = lg[1], l2 = lg[2], l3 = lg[3], l4 = lg[4];
        float m = fmaxf(fmaxf(fmaxf(l0, l1), fmaxf(l2, l3)), l4);
        float e0 = __expf(l0 - m), e1 = __expf(l1 - m), e2 = __expf(l2 - m);
        float e3 = __expf(l3 - m), e4 = __expf(l4 - m);
        float s = ((e0 + e1) + (e2 + e3)) + e4;
        float ps = __builtin_amdgcn_rcpf(s);     // p* (argmax prob, ~3e-6 rel err)
        int cs = (l4 == m) ? 4 : (l3 == m) ? 3 : (l2 == m) ? 2 : (l1 == m) ? 1 : 0;

        bool pass = (ps >= PREF);
        u64 mk = __ballot(pass);
        if (mk) {
            u32 base = 0;
            if (lane == 0) base = atomicAdd(&lcnt, (u32)__popcll(mk));
            base = __shfl((int)base, 0, 64);
            if (pass) {
                u32 fb = __float_as_uint(ps);
                fb = fb > 0x3F7FFFFFu ? 0x3F7FFFFFu : fb;     // clamp p=1.0
                u32 key = (((fb >> 8) & 0x7FFFu) << 17) | ((u32)cs << 14) | (u32)q;
                u32 slot = base + (u32)__popcll(mk & ((1ull << lane) - 1ull));
                if (slot < LCAP) L[slot] = key;
            }
        }
    }
    __syncthreads();

    const u32 n = lcnt < LCAP ? lcnt : LCAP;
    if (tid == 0 && lcnt > LCAP) atomicOr(&flags, 0x1Fu);    // all-brute

    // ---------------- A2a: 15 waves = 5 classes x 3 slices ----------------
    if (wv < 15) {
        int c = wv % 5, sl = wv / 5;
        u32 t4[4] = {0u, 0u, 0u, 0u};
        u32 cnt = 0u;
        for (u32 j = (u32)(sl * 64 + lane); j < n; j += 192u) {
            u32 k = L[j];
            if (((k >> 14) & 7u) == (u32)c) { uinsert_desc(t4, k); ++cnt; }
        }
        #pragma unroll
        for (int d = 1; d < 64; d <<= 1) {
            u32 b0 = (u32)__shfl_xor((int)t4[0], d, 64);
            u32 b1 = (u32)__shfl_xor((int)t4[1], d, 64);
            u32 b2 = (u32)__shfl_xor((int)t4[2], d, 64);
            u32 b3 = (u32)__shfl_xor((int)t4[3], d, 64);
            umerge4_desc(t4, b0, b1, b2, b3);
            cnt += (u32)__shfl_xor((int)cnt, d, 64);
        }
        if (lane == 0) {
            a2buf[wv][0] = t4[0]; a2buf[wv][1] = t4[1];
            a2buf[wv][2] = t4[2]; a2buf[wv][3] = t4[3];
            a2cnt[wv] = cnt;
        }
    }
    __syncthreads();

    // ---------------- A2b: final per-class threshold ----------------
    if (tid < NC) {
        u32 t4[4] = {a2buf[tid][0], a2buf[tid][1], a2buf[tid][2], a2buf[tid][3]};
        umerge4_desc(t4, a2buf[tid + 5][0], a2buf[tid + 5][1], a2buf[tid + 5][2], a2buf[tid + 5][3]);
        umerge4_desc(t4, a2buf[tid + 10][0], a2buf[tid + 10][1], a2buf[tid + 10][2], a2buf[tid + 10][3]);
        u32 cnt = a2cnt[tid] + a2cnt[tid + 5] + a2cnt[tid + 10];
        float p4 = __uint_as_float(0x3F000000u | ((t4[3] >> 17) << 8));  // <= true P4*
        float T = p4 - SLACK;
        Tsh[tid] = T;
        if (cnt < 4u || T < PREF) atomicOr(&flags, 1u << tid);
    }
    __syncthreads();

    // ---------------- B2: filter L; exact p for accepted ----------------
    {
        u32 fl = flags;
        for (u32 j = (u32)tid; j < n; j += 1024u) {
            u32 k = L[j];
            u32 c = (k >> 14) & 7u;
            if ((fl >> c) & 1u) continue;
            float pf = __uint_as_float(0x3F000000u | ((k >> 17) << 8));
            if (pf >= Tsh[c] - B2EPS) {
                u32 q = k & 0x3FFFu;
                const float* lg = lgb + (size_t)q * NC;
                SOFTMAX5(lg, x0, x1, x2, x3, x4, s);
                float num = (c == 0) ? x0 : (c == 1) ? x1 : (c == 2) ? x2 : (c == 3) ? x3 : x4;
                float pe = num / s;              // exact numerics (matches prior rounds)
                u32 slot = atomicAdd(&lcount[c], 1u);
                if (slot < CAP) lists[c][slot] = ((u64)__float_as_uint(pe) << 32) | q;
            }
        }
    }
    __syncthreads();
    if (tid < NC && lcount[tid] > CAP) atomicOr(&flags, 1u << tid);
    __syncthreads();

    // ---------------- phase C: exact keyed top-4 per gt (2 gts/wave) ----------------
    const float2* pc = reinterpret_cast<const float2*>(pred_coords) + (size_t)b * NQ;
    const u32 fl2 = flags;
    #pragma unroll 1
    for (int i = 0; i < 2; ++i) {
        int g = part * (NG / BPB) + i * 16 + wv;
        int m = gt_masks[b * NG + g];
        u64 kk[4] = {~0ull, ~0ull, ~0ull, ~0ull};
        if (m) {
            int c = gt_labels[b * NG + g];
            float2 gc = reinterpret_cast<const float2*>(gt_coords)[(size_t)b * NG + g];
            float gx = gc.x, gy = gc.y, gb2 = gc.x * gc.x + gc.y * gc.y;
            if (!((fl2 >> c) & 1u)) {
                u32 nn = lcount[c];
                for (u32 j = (u32)lane; j < nn; j += 64u) {
                    u64 e = lists[c][j];
                    float p = __uint_as_float((unsigned)(e >> 32));
                    unsigned qq = (unsigned)(e & 0xFFFFFFFFu);
                    float2 cq = pc[qq];
                    float d2 = fmaxf(cq.x * cq.x + cq.y * cq.y + gb2
                                     - 2.0f * (cq.x * gx + cq.y * gy), 0.0f);
                    kinsert(kk, 0.1f * sqrtf(d2) - p, qq);
                }
            } else {
                // flagged class: exact brute scan (same numerics, always correct)
                for (int q2 = lane; q2 < NQ; q2 += 64) {
                    const float* lg2 = lgb + (size_t)q2 * NC;
                    SOFTMAX5(lg2, y0, y1, y2, y3, y4, s2);
                    float num = (c == 0) ? y0 : (c == 1) ? y1 : (c == 2) ? y2 : (c == 3) ? y3 : y4;
                    float p = num / s2;
                    float2 cq = pc[q2];
                    float d2 = fmaxf(cq.x * cq.x + cq.y * cq.y + gb2
                                     - 2.0f * (cq.x * gx + cq.y * gy), 0.0f);
                    kinsert(kk, 0.1f * sqrtf(d2) - p, (unsigned)q2);
                }
            }
            #pragma unroll
            for (int d = 1; d < 64; d <<= 1) {
                u64 b0 = __shfl_xor(kk[0], d, 64);
                u64 b1 = __shfl_xor(kk[1], d, 64);
                u64 b2_ = __shfl_xor(kk[2], d, 64);
                u64 b3 = __shfl_xor(kk[3], d, 64);
                merge4(kk, b0, b1, b2_, b3);
            }
        }
        if (lane < 4) {
            u64 sel = (lane == 0) ? kk[0] : (lane == 1) ? kk[1] : (lane == 2) ? kk[2] : kk[3];
            int idx = m ? (int)(sel & 0xFFFFFFFFull) : lane;
            out[((size_t)(b * 4 + lane) << 10) + g] = idx;
        }
    }
}

extern "C" void kernel_launch(void* const* d_in, const int* in_sizes, int n_in,
                              void* d_out, int out_size, void* d_ws, size_t ws_size,
                              hipStream_t stream) {
    const float* pred_coords = (const float*)d_in[0];
    const float* pred_logits = (const float*)d_in[1];
    const float* gt_coords   = (const float*)d_in[2];
    const int*   gt_labels   = (const int*)d_in[3];
    const int*   gt_masks    = (const int*)d_in[4];
    int* out = (int*)d_out;

    fused_kernel<<<BS * BPB, 1024, 0, stream>>>(
        pred_coords, pred_logits, gt_coords, gt_labels, gt_masks, out);
}